// Round 11
// baseline (252.224 us; speedup 1.0000x reference)
//
#include <hip/hip_runtime.h>
#include <hip/hip_fp16.h>
#include <hip/hip_cooperative_groups.h>
#include <math.h>

namespace cg = cooperative_groups;

#define N_MESH   5151
#define NB       8
#define TT       2048
#define HID      256
#define NLAYERS  3
#define NCHUNK   16
#define CHUNK    128           // TT / NCHUNK
#define NG       101           // threshold grid values 0..100
#define TROW     136           // tab row stride (ushort)
#define NPAD     6144
#define NBLK     6             // scan n-blocks (1024 pts each, 4/thread)
#define SCAN_GRID (NBLK * NB * NCHUNK)   // 768
#define PREP_NBLK 96
#define MLP_NBLK  162          // 162*32 = 5184 >= 5151
#define PH2_NBLK  192          // 24 x 8

// smem layout (bytes): hs2 @0 (528), sgv @528 (512), tab @1040 (27472)
#define OFF_SGV   528
#define OFF_TAB   1040
#define OFF_RED   28512        // kB: 4 waves x 64 floats
#define SMEMA     28512
#define SMEMB     29536

// ws layout (floats)
#define WS_DENSITY 0           // 5151
#define WS_SUM     5184        // 1
#define WS_PART    6144        // NB*NBLK*4*TT = 393216 -> ends 399360
                               // [WT aliases first 98304 floats: dead before kB]
#define WS_PQ      399360      // NCHUNK*NB*NPAD*2 = 1572864 -> ends 1972224

// out layout (floats)
#define OUT_BNORM  0           // 16384
#define OUT_DENSB  16384       // 41208
#define OUT_M      57592       // 16384
#define OUT_S0     73976       // 41208
#define OUT_MESHB  115184      // 82416

typedef _Float16 half8  __attribute__((ext_vector_type(8)));
typedef unsigned short u16x8 __attribute__((ext_vector_type(8)));
typedef float    f32x4  __attribute__((ext_vector_type(4)));

__device__ __forceinline__ float sigmoid_fast(float x) {
    float e = __expf(-x);
    return __builtin_amdgcn_rcpf(1.0f + e);
}

// hA byte offset with XOR swizzle (row stride 512 B fp16)
__device__ __forceinline__ int swz(int row, int kbyte) {
    return row * 512 + (kbyte ^ ((row & 7) << 4));
}

// 16-lane sum via DPP (VALU pipe, zero DS ops)
__device__ __forceinline__ float dpp16_sum(float v) {
    int a;
    a = __builtin_amdgcn_update_dpp(0, __float_as_int(v), 0xB1, 0xF, 0xF, true);
    v += __int_as_float(a);
    a = __builtin_amdgcn_update_dpp(0, __float_as_int(v), 0x4E, 0xF, 0xF, true);
    v += __int_as_float(a);
    a = __builtin_amdgcn_update_dpp(0, __float_as_int(v), 0x141, 0xF, 0xF, true);
    v += __int_as_float(a);
    a = __builtin_amdgcn_update_dpp(0, __float_as_int(v), 0x140, 0xF, 0xF, true);
    v += __int_as_float(a);
    return v;
}

// Direction-resolved A-table, [g][t] layout (fp16), conflict-free build.
__device__ __forceinline__ void build_table(int tid, const float* hs2,
                                            float* sgv, unsigned short* tab)
{
    if (tid < CHUNK) sgv[tid] = (hs2[tid + 1] >= hs2[tid]) ? 1.0f : -1.0f;
    for (int idx = tid; idx < NG * CHUNK; idx += 256) {
        int g = idx >> 7;
        int t = idx & 127;
        float ht = hs2[t + 1];
        bool inc = (ht >= hs2[t]);
        float bx = ht * 1000.0f;
        float y = inc ? fmaf(-10.f, (float)g, bx) : fmaf(10.f, (float)g, -bx);
        float A = __builtin_amdgcn_rcpf(1.0f + __expf(y));
        tab[g * TROW + t] = __half_as_ushort(__float2half(A));
    }
}

// ---------------------------------------------------------------------------
// kA: stage1 = scan phase1 (all 768 blocks) + prep (blocks 0..95).
//     grid.sync (coop) / kernel split (fallback).
//     stage2 = MLP (blocks 0..161, 32 rows) | phase2 (blocks 162..353).
// stage: 0 = stage1 only, 1 = stage2 only, 2 = both with grid sync.
// ---------------------------------------------------------------------------
__global__ __launch_bounds__(256, 3) void kA(
    int stage,
    const float* __restrict__ dec, const float* __restrict__ y0,
    const float* __restrict__ mesh, const float* __restrict__ Wblk,
    const float* __restrict__ Win,  const float* __restrict__ bin,
    const float* __restrict__ bblk, const float* __restrict__ Wout,
    const float* __restrict__ bout, const float* __restrict__ s0_in,
    float2* __restrict__ PQ, half8* __restrict__ WT,
    float* __restrict__ density)
{
    __shared__ __align__(16) char smem[SMEMA];
    const int tid = threadIdx.x;
    const int bid = blockIdx.x;

    if (stage != 1) {
        // ---- prep: W fragment gather (blocks 0..95) ----
        if (bid < PREP_NBLK) {
            int g = bid * 256 + tid;            // [0, 24576)
            int l  = g & 63;
            int nt = (g >> 6) & 15;
            int kg = (g >> 10) & 7;
            int L  = g >> 13;
            int n  = nt * 16 + (l & 15);
            int kb = kg * 32 + ((l >> 4) & 3) * 8;
            const float* Wb = Wblk + (size_t)L * HID * HID;
            half8 v;
#pragma unroll
            for (int i = 0; i < 8; ++i)
                v[i] = (_Float16)Wb[(size_t)(kb + i) * HID + n];
            WT[g] = v;
        }
        // ---- scan phase1 (all blocks) ----
        {
            float* hs2 = (float*)smem;
            float* sgv = (float*)(smem + OFF_SGV);
            unsigned short* tab = (unsigned short*)(smem + OFF_TAB);

            const int nb = bid % NBLK;
            const int rem = bid / NBLK;
            const int b = rem & 7;
            const int c = rem >> 3;
            const int t0 = c * CHUNK;

            if (tid < CHUNK) hs2[tid + 1] = dec[b * TT + t0 + tid];
            if (tid == 0) hs2[0] = (c == 0) ? y0[b] : dec[b * TT + t0 - 1];

            int ga[4], gb[4];
#pragma unroll
            for (int q = 0; q < 4; ++q) {
                int n = nb * 1024 + q * 256 + tid;
                if (n < N_MESH) {
                    gb[q] = (int)(mesh[2 * n]     * 100.0f + 0.5f);
                    ga[q] = (int)(mesh[2 * n + 1] * 100.0f + 0.5f);
                } else { ga[q] = 0; gb[q] = 0; }
            }
            __syncthreads();
            build_table(tid, hs2, sgv, tab);
            __syncthreads();

            float P[4] = {1.f, 1.f, 1.f, 1.f};
            float R[4];
            float gprev = sgv[0];
#pragma unroll
            for (int q = 0; q < 4; ++q) R[q] = -gprev;

            for (int tb = 0; tb < CHUNK; tb += 8) {
                u16x8 ra[4], rb[4];
#pragma unroll
                for (int q = 0; q < 4; ++q) {
                    ra[q] = *(const u16x8*)&tab[ga[q] * TROW + tb];
                    rb[q] = *(const u16x8*)&tab[gb[q] * TROW + tb];
                }
                float4 sA = *(const float4*)&sgv[tb];
                float4 sB = *(const float4*)&sgv[tb + 4];
                float sg8[8] = {sA.x, sA.y, sA.z, sA.w, sB.x, sB.y, sB.z, sB.w};
#pragma unroll
                for (int j = 0; j < 8; ++j) {
                    float sgt = sg8[j];
                    float dl = gprev - sgt;
                    gprev = sgt;
                    bool inc = sgt > 0.0f;
#pragma unroll
                    for (int q = 0; q < 4; ++q) {
                        unsigned short u = inc ? ra[q][j] : rb[q][j];
                        float A = __half2float(__ushort_as_half(u));
                        float r = R[q] + dl;
                        P[q] *= A;
                        R[q] = r * A;
                    }
                }
            }
            size_t basew = ((size_t)(c * NB + b)) * NPAD;
#pragma unroll
            for (int q = 0; q < 4; ++q) {
                int n = nb * 1024 + q * 256 + tid;
                float2 v; v.x = P[q]; v.y = R[q] + gprev;
                PQ[basew + n] = v;
            }
        }
    }

    if (stage == 2) cg::this_grid().sync();

    if (stage != 0) {
        if (bid < MLP_NBLK) {
            // ---- density MLP: 32 rows, 4 waves = (mt 0..1) x (nh 0..1) ----
            char* hA = smem;                              // 32 x 512 B
            float* psum = (float*)(smem + 16384);         // [2][16][2]
            const int w = tid >> 6;
            const int lane = tid & 63;
            const int rl = lane & 15;
            const int cgi = lane >> 4;
            const int mt = w & 1;
            const int nh = w >> 1;
            const int row0 = bid * 32;

            // input layer
            {
                float m0[4], m1[4];
#pragma unroll
                for (int r = 0; r < 4; ++r) {
                    int gr = row0 + mt * 16 + cgi * 4 + r;
                    if (gr < N_MESH) { m0[r] = mesh[2 * gr]; m1[r] = mesh[2 * gr + 1]; }
                    else { m0[r] = 0.f; m1[r] = 0.f; }
                }
#pragma unroll
                for (int j = 0; j < 8; ++j) {
                    int col = nh * 128 + j * 16 + rl;
                    float wa = Win[col], wb = Win[HID + col], bi = bin[col];
#pragma unroll
                    for (int r = 0; r < 4; ++r) {
                        float v = fmaxf(fmaf(m0[r], wa, fmaf(m1[r], wb, bi)), 0.f);
                        *(_Float16*)(hA + swz(mt * 16 + cgi * 4 + r, col * 2)) =
                            (_Float16)v;
                    }
                }
            }
            __syncthreads();

            float p[4] = {0.f, 0.f, 0.f, 0.f};
            for (int L = 0; L < NLAYERS; ++L) {
                half8 af[8];
#pragma unroll
                for (int kg = 0; kg < 8; ++kg)
                    af[kg] = *(const half8*)(hA + swz(mt * 16 + rl,
                                                      kg * 64 + cgi * 16));
                __syncthreads();

                float bias[8];
#pragma unroll
                for (int j = 0; j < 8; ++j)
                    bias[j] = bblk[L * HID + nh * 128 + j * 16 + rl];

                f32x4 acc[8];
#pragma unroll
                for (int j = 0; j < 8; ++j) acc[j] = (f32x4){0.f, 0.f, 0.f, 0.f};

                const half8* WTL = WT + ((size_t)(L * 8) * 16 + nh * 8) * 64 + lane;
                half8 b0[8], b1[8];
#pragma unroll
                for (int j = 0; j < 8; ++j) b0[j] = WTL[(size_t)j * 64];
#pragma unroll
                for (int kg2 = 0; kg2 < 8; kg2 += 2) {
#pragma unroll
                    for (int j = 0; j < 8; ++j)
                        b1[j] = WTL[(size_t)(kg2 + 1) * 1024 + (size_t)j * 64];
#pragma unroll
                    for (int j = 0; j < 8; ++j)
                        acc[j] = __builtin_amdgcn_mfma_f32_16x16x32_f16(
                            af[kg2], b0[j], acc[j], 0, 0, 0);
                    if (kg2 + 2 < 8) {
#pragma unroll
                        for (int j = 0; j < 8; ++j)
                            b0[j] = WTL[(size_t)(kg2 + 2) * 1024 + (size_t)j * 64];
                    }
#pragma unroll
                    for (int j = 0; j < 8; ++j)
                        acc[j] = __builtin_amdgcn_mfma_f32_16x16x32_f16(
                            af[kg2 + 1], b1[j], acc[j], 0, 0, 0);
                }

                // epilogue: RMW h in LDS (fp16); last layer fuses Wout
#pragma unroll
                for (int j = 0; j < 8; ++j) {
                    int col = nh * 128 + j * 16 + rl;
                    float wo = (L == NLAYERS - 1) ? Wout[col] : 0.f;
#pragma unroll
                    for (int r = 0; r < 4; ++r) {
                        int off = swz(mt * 16 + cgi * 4 + r, col * 2);
                        float hp = (float)(*(_Float16*)(hA + off));
                        float v = hp + fmaxf(acc[j][r] + bias[j], 0.f);
                        if (L < NLAYERS - 1)
                            *(_Float16*)(hA + off) = (_Float16)v;
                        else
                            p[r] = fmaf(v, wo, p[r]);
                    }
                }
                if (L < NLAYERS - 1) __syncthreads();
            }

            // reduce p over the 16 lanes of each (cgi) group
#pragma unroll
            for (int st = 1; st < 16; st <<= 1)
#pragma unroll
                for (int r = 0; r < 4; ++r) p[r] += __shfl_xor(p[r], st, 64);
            if (rl == 0) {
#pragma unroll
                for (int r = 0; r < 4; ++r)
                    psum[(mt * 16 + cgi * 4 + r) * 2 + nh] = p[r];
            }
            __syncthreads();
            if (tid < 32) {
                int gr = row0 + tid;
                float pp = psum[tid * 2] + psum[tid * 2 + 1];
                if (gr < N_MESH) density[gr] = sigmoid_fast(pp + bout[0]);
            }
        } else if (bid < MLP_NBLK + PH2_NBLK) {
            // ---- phase2: chunk-boundary states into PQ .x slot ----
            int idx = bid - MLP_NBLK;
            int nbb = idx % 24;
            int b = idx / 24;
            int n = nbb * 256 + tid;
            float* PQf = (float*)PQ;
            float2 v[NCHUNK];
#pragma unroll
            for (int c = 0; c < NCHUNK; ++c)
                v[c] = PQ[((size_t)(c * NB + b)) * NPAD + n];
            float s = (n < N_MESH) ? s0_in[b * N_MESH + n] : 0.f;
#pragma unroll
            for (int c = 0; c < NCHUNK; ++c) {
                size_t ix = ((size_t)(c * NB + b)) * NPAD + n;
                PQf[2 * ix] = s;
                s = fmaf(v[c].x, s, v[c].y);
            }
        }
    }
}

// ---------------------------------------------------------------------------
// kB: stage1 = phase3 (blocks 0..767) + density sum (block 768).
//     stage2 = outputs (blocks 0..707).
// ---------------------------------------------------------------------------
__global__ __launch_bounds__(256, 4) void kB(
    int stage,
    const float* __restrict__ dec, const float* __restrict__ y0,
    const float* __restrict__ mesh, const float* __restrict__ density,
    const float* __restrict__ s0_in, float* __restrict__ PQf,
    float* __restrict__ partials, float* __restrict__ sum_ptr,
    float* __restrict__ out)
{
    __shared__ __align__(16) char smem[SMEMB];
    const int tid = threadIdx.x;
    const int bid = blockIdx.x;

    if (stage != 1) {
        if (bid < SCAN_GRID) {
            // ---- phase3 replay ----
            float* hs2 = (float*)smem;
            float* sgv = (float*)(smem + OFF_SGV);
            unsigned short* tab = (unsigned short*)(smem + OFF_TAB);
            float* red = (float*)(smem + OFF_RED);

            const int nb = bid % NBLK;
            const int rem = bid / NBLK;
            const int b = rem & 7;
            const int c = rem >> 3;
            const int t0 = c * CHUNK;
            const int lane = tid & 63, w = tid >> 6;

            if (tid < CHUNK) hs2[tid + 1] = dec[b * TT + t0 + tid];
            if (tid == 0) hs2[0] = (c == 0) ? y0[b] : dec[b * TT + t0 - 1];
            __syncthreads();
            build_table(tid, hs2, sgv, tab);
            __syncthreads();

            int ga[4], gb[4];
            float d[4], z[4];
            float gprev = sgv[0];
#pragma unroll
            for (int q = 0; q < 4; ++q) {
                int n = nb * 1024 + q * 256 + tid;
                float S = 0.f;
                if (n < N_MESH) {
                    gb[q] = (int)(mesh[2 * n]     * 100.0f + 0.5f);
                    ga[q] = (int)(mesh[2 * n + 1] * 100.0f + 0.5f);
                    d[q]  = density[n];
                    S = PQf[2 * (((size_t)(c * NB + b)) * NPAD + n)];
                } else { ga[q] = 0; gb[q] = 0; d[q] = 0.f; }
                z[q] = S - gprev;
            }

            float* pout = partials + ((size_t)((b * NBLK + nb) * 4 + w)) * TT + t0;

            for (int tb = 0; tb < CHUNK; tb += 16) {
                float v[16];
#pragma unroll
                for (int hh = 0; hh < 2; ++hh) {
                    int tw = tb + hh * 8;
                    u16x8 ra[4], rb[4];
#pragma unroll
                    for (int q = 0; q < 4; ++q) {
                        ra[q] = *(const u16x8*)&tab[ga[q] * TROW + tw];
                        rb[q] = *(const u16x8*)&tab[gb[q] * TROW + tw];
                    }
                    float4 sA = *(const float4*)&sgv[tw];
                    float4 sB = *(const float4*)&sgv[tw + 4];
                    float sg8[8] = {sA.x, sA.y, sA.z, sA.w,
                                    sB.x, sB.y, sB.z, sB.w};
#pragma unroll
                    for (int j = 0; j < 8; ++j) {
                        float sgt = sg8[j];
                        float dl = gprev - sgt;
                        gprev = sgt;
                        bool inc = sgt > 0.0f;
#pragma unroll
                        for (int q = 0; q < 4; ++q) {
                            unsigned short u = inc ? ra[q][j] : rb[q][j];
                            float A = __half2float(__ushort_as_half(u));
                            z[q] = (z[q] + dl) * A;
                        }
                        float a0 = d[0] * z[0];
                        float a1 = d[1] * z[1];
                        a0 = fmaf(d[2], z[2], a0);
                        a1 = fmaf(d[3], z[3], a1);
                        v[hh * 8 + j] = a0 + a1;
                    }
                }
#pragma unroll
                for (int j = 0; j < 16; ++j) v[j] = dpp16_sum(v[j]);
                float outv = v[0];
#pragma unroll
                for (int j = 1; j < 16; ++j) if ((lane & 15) == j) outv = v[j];
                red[w * 64 + (lane & 15) * 4 + (lane >> 4)] = outv;
                if (lane < 16) {
                    float4 s4 = *(const float4*)&red[w * 64 + lane * 4];
                    pout[tb + lane] = (s4.x + s4.y) + (s4.z + s4.w);
                }
            }
        } else {
            // ---- density sum (block 768) ----
            float* red4 = (float*)smem;
            float pp = 0.f;
            for (int i = tid; i < N_MESH; i += 256) pp += density[i];
#pragma unroll
            for (int st = 1; st < 64; st <<= 1) pp += __shfl_xor(pp, st, 64);
            int lane = tid & 63, w = tid >> 6;
            if (lane == 0) red4[w] = pp;
            __syncthreads();
            if (tid == 0) sum_ptr[0] = red4[0] + red4[1] + red4[2] + red4[3];
        }
    }

    if (stage == 2) cg::this_grid().sync();

    if (stage != 0) {
        int i = bid * 256 + tid;
        const int NM = NB * TT;
        if (i < NM) {
            int b = i >> 11, t = i & (TT - 1);
            float h  = dec[b * TT + t];
            float hp = t ? dec[b * TT + t - 1] : y0[b];
            float g  = (h >= hp) ? 1.0f : -1.0f;
            float acc = 0.f;
#pragma unroll 8
            for (int k = 0; k < NBLK * 4; ++k)
                acc += partials[((size_t)(b * NBLK * 4 + k)) * TT + t];
            float D = sum_ptr[0];
            float m = (acc + g * D) / D;
            out[OUT_M + i] = m;
            out[OUT_BNORM + i] = 0.5f * m + 0.5f;
        } else {
            int j = i - NM;
            const int n1 = NB * N_MESH;
            if (j < n1) {
                out[OUT_DENSB + j] = density[j % N_MESH];
            } else if (j < 2 * n1) {
                int jj = j - n1;
                out[OUT_S0 + jj] = s0_in[jj];
            } else if (j < 4 * n1) {
                int jj = j - 2 * n1;
                out[OUT_MESHB + jj] = mesh[jj % (2 * N_MESH)];
            }
        }
    }
}

extern "C" void kernel_launch(void* const* d_in, const int* in_sizes, int n_in,
                              void* d_out, int out_size, void* d_ws, size_t ws_size,
                              hipStream_t stream) {
    const float* dec  = (const float*)d_in[1];
    const float* s0   = (const float*)d_in[2];
    const float* y0   = (const float*)d_in[3];
    const float* mesh = (const float*)d_in[4];
    const float* Win  = (const float*)d_in[5];
    const float* bin  = (const float*)d_in[6];
    const float* Wblk = (const float*)d_in[7];
    const float* bblk = (const float*)d_in[8];
    const float* Wout = (const float*)d_in[9];
    const float* bout = (const float*)d_in[10];
    float* out = (float*)d_out;
    float* ws  = (float*)d_ws;

    float*  density  = ws + WS_DENSITY;
    float*  sum_ptr  = ws + WS_SUM;
    float*  partials = ws + WS_PART;
    float*  pqf      = ws + WS_PQ;
    float2* pq       = (float2*)pqf;
    half8*  wt       = (half8*)(ws + WS_PART);   // aliases partials (dead by kB)

    int stage2 = 2;
    void* argsA[] = { &stage2, (void*)&dec, (void*)&y0, (void*)&mesh,
                      (void*)&Wblk, (void*)&Win, (void*)&bin, (void*)&bblk,
                      (void*)&Wout, (void*)&bout, (void*)&s0,
                      (void*)&pq, (void*)&wt, (void*)&density };
    hipError_t eA = hipLaunchCooperativeKernel((void*)kA, dim3(SCAN_GRID),
                                               dim3(256), argsA, 0, stream);
    if (eA != hipSuccess) {
        kA<<<SCAN_GRID, 256, 0, stream>>>(0, dec, y0, mesh, Wblk, Win, bin,
                                          bblk, Wout, bout, s0, pq, wt, density);
        kA<<<MLP_NBLK + PH2_NBLK, 256, 0, stream>>>(1, dec, y0, mesh, Wblk,
                                                    Win, bin, bblk, Wout, bout,
                                                    s0, pq, wt, density);
    }

    void* argsB[] = { &stage2, (void*)&dec, (void*)&y0, (void*)&mesh,
                      (void*)&density, (void*)&s0, (void*)&pqf,
                      (void*)&partials, (void*)&sum_ptr, (void*)&out };
    hipError_t eB = hipLaunchCooperativeKernel((void*)kB, dim3(SCAN_GRID + 1),
                                               dim3(256), argsB, 0, stream);
    if (eB != hipSuccess) {
        kB<<<SCAN_GRID + 1, 256, 0, stream>>>(0, dec, y0, mesh, density, s0,
                                              pqf, partials, sum_ptr, out);
        kB<<<708, 256, 0, stream>>>(1, dec, y0, mesh, density, s0,
                                    pqf, partials, sum_ptr, out);
    }
}

// Round 12
// 82.659 us; speedup vs baseline: 3.0514x; 3.0514x over previous
//
#include <hip/hip_runtime.h>
#include <hip/hip_fp16.h>
#include <math.h>

#define N_MESH   5151
#define NB       8
#define TT       2048
#define HID      256
#define NLAYERS  3
#define NCHUNK   16
#define CHUNK    128           // TT / NCHUNK
#define NG       101           // threshold grid values 0..100
#define TROW     136           // tab row stride (ushort)
#define NPAD     6144
#define NBLK     6             // scan n-blocks (1024 pts each, 4/thread)
#define SCAN_GRID (NBLK * NB * NCHUNK)   // 768
#define PREP_NBLK 96
#define MLP_NBLK  81           // 81*64 = 5184 >= 5151 (512-thr blocks)
#define PH2_NBLK  96           // 12 x 8 (512-thr blocks)

// scan smem layout (bytes): hs2 @0 (528), sgv @528 (512), tab @1040 (27472)
#define OFF_SGV   528
#define OFF_TAB   1040
#define OFF_RED   28512        // k3: 4 waves x 64 floats
#define SMEM1     28512
#define SMEM3     29536

// ws layout (floats)
#define WS_DENSITY 0           // 5151
#define WS_SUM     5184        // 1
#define WS_PART    6144        // NB*NBLK*4*TT = 393216 -> ends 399360
                               // [WT aliases first 98304 floats: dead before k3]
#define WS_PQ      399360      // NCHUNK*NB*NPAD*2 = 1572864 -> ends 1972224

// out layout (floats)
#define OUT_BNORM  0           // 16384
#define OUT_DENSB  16384       // 41208
#define OUT_M      57592       // 16384
#define OUT_S0     73976       // 41208
#define OUT_MESHB  115184      // 82416

typedef _Float16 half8  __attribute__((ext_vector_type(8)));
typedef unsigned short u16x8 __attribute__((ext_vector_type(8)));
typedef float    f32x4  __attribute__((ext_vector_type(4)));

__device__ __forceinline__ float sigmoid_fast(float x) {
    float e = __expf(-x);
    return __builtin_amdgcn_rcpf(1.0f + e);
}

// hA byte offset with XOR swizzle (row stride 512 B fp16)
__device__ __forceinline__ int swz(int row, int kbyte) {
    return row * 512 + (kbyte ^ ((row & 7) << 4));
}

// 16-lane sum via DPP (VALU pipe, zero DS ops)
__device__ __forceinline__ float dpp16_sum(float v) {
    int a;
    a = __builtin_amdgcn_update_dpp(0, __float_as_int(v), 0xB1, 0xF, 0xF, true);
    v += __int_as_float(a);
    a = __builtin_amdgcn_update_dpp(0, __float_as_int(v), 0x4E, 0xF, 0xF, true);
    v += __int_as_float(a);
    a = __builtin_amdgcn_update_dpp(0, __float_as_int(v), 0x141, 0xF, 0xF, true);
    v += __int_as_float(a);
    a = __builtin_amdgcn_update_dpp(0, __float_as_int(v), 0x140, 0xF, 0xF, true);
    v += __int_as_float(a);
    return v;
}

// Direction-resolved A-table, [g][t] layout (fp16), conflict-free build.
__device__ __forceinline__ void build_table(int tid, const float* hs2,
                                            float* sgv, unsigned short* tab)
{
    if (tid < CHUNK) sgv[tid] = (hs2[tid + 1] >= hs2[tid]) ? 1.0f : -1.0f;
    for (int idx = tid; idx < NG * CHUNK; idx += 256) {
        int g = idx >> 7;
        int t = idx & 127;
        float ht = hs2[t + 1];
        bool inc = (ht >= hs2[t]);
        float bx = ht * 1000.0f;
        float y = inc ? fmaf(-10.f, (float)g, bx) : fmaf(10.f, (float)g, -bx);
        float A = __builtin_amdgcn_rcpf(1.0f + __expf(y));
        tab[g * TROW + t] = __half_as_ushort(__float2half(A));
    }
}

// ---------------------------------------------------------------------------
// k1: blocks [0,768) scan phase1; blocks [768,864) W-fragment gather (prep).
// (proven R10 body)
// ---------------------------------------------------------------------------
__global__ __launch_bounds__(256) void k1_scan1_prep(
    const float* __restrict__ dec, const float* __restrict__ y0,
    const float* __restrict__ mesh, const float* __restrict__ Wblk,
    float2* __restrict__ PQ, half8* __restrict__ WT)
{
    __shared__ __align__(16) char smem[SMEM1];
    const int tid = threadIdx.x;

    if (blockIdx.x >= SCAN_GRID) {
        int g = (blockIdx.x - SCAN_GRID) * 256 + tid;   // [0, 24576)
        int l  = g & 63;
        int nt = (g >> 6) & 15;
        int kg = (g >> 10) & 7;
        int L  = g >> 13;
        int n  = nt * 16 + (l & 15);
        int kb = kg * 32 + ((l >> 4) & 3) * 8;
        const float* Wb = Wblk + (size_t)L * HID * HID;
        half8 v;
#pragma unroll
        for (int i = 0; i < 8; ++i)
            v[i] = (_Float16)Wb[(size_t)(kb + i) * HID + n];
        WT[g] = v;
        return;
    }

    float* hs2 = (float*)smem;
    float* sgv = (float*)(smem + OFF_SGV);
    unsigned short* tab = (unsigned short*)(smem + OFF_TAB);

    const int sb = blockIdx.x;
    const int nb = sb % NBLK;
    const int rem = sb / NBLK;
    const int b = rem & 7;
    const int c = rem >> 3;
    const int t0 = c * CHUNK;

    if (tid < CHUNK) hs2[tid + 1] = dec[b * TT + t0 + tid];
    if (tid == 0) hs2[0] = (c == 0) ? y0[b] : dec[b * TT + t0 - 1];

    int ga[4], gb[4];
#pragma unroll
    for (int q = 0; q < 4; ++q) {
        int n = nb * 1024 + q * 256 + tid;
        if (n < N_MESH) {
            gb[q] = (int)(mesh[2 * n]     * 100.0f + 0.5f);
            ga[q] = (int)(mesh[2 * n + 1] * 100.0f + 0.5f);
        } else { ga[q] = 0; gb[q] = 0; }
    }
    __syncthreads();
    build_table(tid, hs2, sgv, tab);
    __syncthreads();

    float P[4] = {1.f, 1.f, 1.f, 1.f};
    float R[4];
    float gprev = sgv[0];
#pragma unroll
    for (int q = 0; q < 4; ++q) R[q] = -gprev;

    for (int tb = 0; tb < CHUNK; tb += 8) {
        u16x8 ra[4], rb[4];
#pragma unroll
        for (int q = 0; q < 4; ++q) {
            ra[q] = *(const u16x8*)&tab[ga[q] * TROW + tb];
            rb[q] = *(const u16x8*)&tab[gb[q] * TROW + tb];
        }
        float4 sA = *(const float4*)&sgv[tb];
        float4 sB = *(const float4*)&sgv[tb + 4];
        float sg8[8] = {sA.x, sA.y, sA.z, sA.w, sB.x, sB.y, sB.z, sB.w};
#pragma unroll
        for (int j = 0; j < 8; ++j) {
            float sgt = sg8[j];
            float dl = gprev - sgt;      // 0 or +-2, wave-uniform
            gprev = sgt;
            bool inc = sgt > 0.0f;
#pragma unroll
            for (int q = 0; q < 4; ++q) {
                unsigned short u = inc ? ra[q][j] : rb[q][j];
                float A = __half2float(__ushort_as_half(u));
                float r = R[q] + dl;
                P[q] *= A;
                R[q] = r * A;
            }
        }
    }
    size_t basew = ((size_t)(c * NB + b)) * NPAD;
#pragma unroll
    for (int q = 0; q < 4; ++q) {
        int n = nb * 1024 + q * 256 + tid;
        float2 v; v.x = P[q]; v.y = R[q] + gprev;
        PQ[basew + n] = v;
    }
}

// ---------------------------------------------------------------------------
// k2: blocks [0,81) = MFMA density MLP (proven R10 body, 512 thr);
//     blocks [81,177) = phase2 (512 thr, 12 n-blocks x 8 b).
// ---------------------------------------------------------------------------
__global__ __launch_bounds__(512) void k2_mlp_phase2(
    const float* __restrict__ mesh, const float* __restrict__ Win,
    const float* __restrict__ bin,  const half8* __restrict__ WT,
    const float* __restrict__ bblk, const float* __restrict__ Wout,
    const float* __restrict__ bout, float* __restrict__ density,
    const float* __restrict__ s0_in, float* __restrict__ PQf)
{
    __shared__ __align__(16) char hA[64 * 512];   // 32 KB
    __shared__ float psum[4][16][2];
    const int tid  = threadIdx.x;

    if (blockIdx.x >= MLP_NBLK) {
        // ---- phase2: chunk-boundary states into PQ .x slot ----
        int idx = blockIdx.x - MLP_NBLK;   // 0..95
        int nbb = idx % 12;
        int b   = idx / 12;
        int n   = nbb * 512 + tid;
        const float2* PQ = (const float2*)PQf;
        float2 v[NCHUNK];
#pragma unroll
        for (int c = 0; c < NCHUNK; ++c)
            v[c] = PQ[((size_t)(c * NB + b)) * NPAD + n];
        float s = (n < N_MESH) ? s0_in[b * N_MESH + n] : 0.f;
#pragma unroll
        for (int c = 0; c < NCHUNK; ++c) {
            size_t ix = ((size_t)(c * NB + b)) * NPAD + n;
            PQf[2 * ix] = s;                 // boundary state for chunk c
            s = fmaf(v[c].x, s, v[c].y);
        }
        return;
    }

    // ---- density MLP (proven R10 k_mlp body) ----
    const int w    = tid >> 6;
    const int lane = tid & 63;
    const int rl   = lane & 15;
    const int cg   = lane >> 4;
    const int mt   = w & 3;
    const int nh   = w >> 2;
    const int row0 = blockIdx.x * 64;

    float hreg[8][4];

    {
        float m0[4], m1[4];
#pragma unroll
        for (int r = 0; r < 4; ++r) {
            int gr = row0 + mt * 16 + cg * 4 + r;
            if (gr < N_MESH) { m0[r] = mesh[2 * gr]; m1[r] = mesh[2 * gr + 1]; }
            else { m0[r] = 0.f; m1[r] = 0.f; }
        }
#pragma unroll
        for (int j = 0; j < 8; ++j) {
            int col = nh * 128 + j * 16 + rl;
            float wa = Win[col], wb = Win[HID + col], bi = bin[col];
#pragma unroll
            for (int r = 0; r < 4; ++r) {
                float v = fmaxf(fmaf(m0[r], wa, fmaf(m1[r], wb, bi)), 0.f);
                hreg[j][r] = v;
                *(_Float16*)(hA + swz(mt * 16 + cg * 4 + r, col * 2)) =
                    (_Float16)v;
            }
        }
    }
    __syncthreads();

    for (int L = 0; L < NLAYERS; ++L) {
        half8 af[8];
#pragma unroll
        for (int kg = 0; kg < 8; ++kg)
            af[kg] = *(const half8*)(hA + swz(mt * 16 + rl, kg * 64 + cg * 16));
        __syncthreads();

        float bias[8];
#pragma unroll
        for (int j = 0; j < 8; ++j)
            bias[j] = bblk[L * HID + nh * 128 + j * 16 + rl];

        f32x4 acc[8];
#pragma unroll
        for (int j = 0; j < 8; ++j) acc[j] = (f32x4){0.f, 0.f, 0.f, 0.f};

        const half8* WTL = WT + ((size_t)(L * 8) * 16 + nh * 8) * 64 + lane;
        half8 b0[8], b1[8];
#pragma unroll
        for (int j = 0; j < 8; ++j) b0[j] = WTL[(size_t)j * 64];
#pragma unroll
        for (int kg2 = 0; kg2 < 8; kg2 += 2) {
#pragma unroll
            for (int j = 0; j < 8; ++j)
                b1[j] = WTL[(size_t)(kg2 + 1) * 1024 + (size_t)j * 64];
#pragma unroll
            for (int j = 0; j < 8; ++j)
                acc[j] = __builtin_amdgcn_mfma_f32_16x16x32_f16(
                    af[kg2], b0[j], acc[j], 0, 0, 0);
            if (kg2 + 2 < 8) {
#pragma unroll
                for (int j = 0; j < 8; ++j)
                    b0[j] = WTL[(size_t)(kg2 + 2) * 1024 + (size_t)j * 64];
            }
#pragma unroll
            for (int j = 0; j < 8; ++j)
                acc[j] = __builtin_amdgcn_mfma_f32_16x16x32_f16(
                    af[kg2 + 1], b1[j], acc[j], 0, 0, 0);
        }

#pragma unroll
        for (int j = 0; j < 8; ++j) {
            int col = nh * 128 + j * 16 + rl;
#pragma unroll
            for (int r = 0; r < 4; ++r) {
                float v = hreg[j][r] + fmaxf(acc[j][r] + bias[j], 0.f);
                hreg[j][r] = v;
                if (L < NLAYERS - 1)
                    *(_Float16*)(hA + swz(mt * 16 + cg * 4 + r, col * 2)) =
                        (_Float16)v;
            }
        }
        if (L < NLAYERS - 1) __syncthreads();
    }

    {
        float p[4] = {0.f, 0.f, 0.f, 0.f};
#pragma unroll
        for (int j = 0; j < 8; ++j) {
            float wo = Wout[nh * 128 + j * 16 + rl];
#pragma unroll
            for (int r = 0; r < 4; ++r) p[r] = fmaf(hreg[j][r], wo, p[r]);
        }
#pragma unroll
        for (int st = 1; st < 16; st <<= 1)
#pragma unroll
            for (int r = 0; r < 4; ++r) p[r] += __shfl_xor(p[r], st, 64);
        if (rl == 0) {
#pragma unroll
            for (int r = 0; r < 4; ++r) psum[mt][cg * 4 + r][nh] = p[r];
        }
    }
    __syncthreads();
    if (tid < 64) {
        int gr = row0 + tid;
        float pp = psum[tid >> 4][tid & 15][0] + psum[tid >> 4][tid & 15][1];
        if (gr < N_MESH) density[gr] = sigmoid_fast(pp + bout[0]);
    }
}

// ---------------------------------------------------------------------------
// k3: blocks [0,768) = phase3 replay (proven R10 body);
//     block 768 = density sum.
// ---------------------------------------------------------------------------
__global__ __launch_bounds__(256) void k3_phase3_sum(
    const float* __restrict__ dec, const float* __restrict__ y0,
    const float* __restrict__ mesh, const float* __restrict__ density,
    const float* __restrict__ PQf, float* __restrict__ partials,
    float* __restrict__ sum_out)
{
    __shared__ __align__(16) char smem[SMEM3];
    const int tid = threadIdx.x;
    const int bx = blockIdx.x;

    if (bx >= SCAN_GRID) {
        // ---- density sum ----
        float* red4 = (float*)smem;
        float p = 0.f;
        for (int i = tid; i < N_MESH; i += 256) p += density[i];
#pragma unroll
        for (int st = 1; st < 64; st <<= 1) p += __shfl_xor(p, st, 64);
        int lane = tid & 63, w = tid >> 6;
        if (lane == 0) red4[w] = p;
        __syncthreads();
        if (tid == 0) sum_out[0] = red4[0] + red4[1] + red4[2] + red4[3];
        return;
    }

    float* hs2 = (float*)smem;
    float* sgv = (float*)(smem + OFF_SGV);
    unsigned short* tab = (unsigned short*)(smem + OFF_TAB);
    float* red = (float*)(smem + OFF_RED);   // [4 waves][64]

    const int nb = bx % NBLK;
    const int rem = bx / NBLK;
    const int b = rem & 7;
    const int c = rem >> 3;
    const int t0 = c * CHUNK;
    const int lane = tid & 63, w = tid >> 6;

    if (tid < CHUNK) hs2[tid + 1] = dec[b * TT + t0 + tid];
    if (tid == 0) hs2[0] = (c == 0) ? y0[b] : dec[b * TT + t0 - 1];
    __syncthreads();
    build_table(tid, hs2, sgv, tab);
    __syncthreads();

    int ga[4], gb[4];
    float d[4], z[4];
    float gprev = sgv[0];
#pragma unroll
    for (int q = 0; q < 4; ++q) {
        int n = nb * 1024 + q * 256 + tid;
        float S = 0.f;
        if (n < N_MESH) {
            gb[q] = (int)(mesh[2 * n]     * 100.0f + 0.5f);
            ga[q] = (int)(mesh[2 * n + 1] * 100.0f + 0.5f);
            d[q]  = density[n];
            S = PQf[2 * (((size_t)(c * NB + b)) * NPAD + n)];
        } else { ga[q] = 0; gb[q] = 0; d[q] = 0.f; }
        z[q] = S - gprev;
    }

    float* pout = partials + ((size_t)((b * NBLK + nb) * 4 + w)) * TT + t0;

    for (int tb = 0; tb < CHUNK; tb += 16) {
        float v[16];
#pragma unroll
        for (int hh = 0; hh < 2; ++hh) {
            int tw = tb + hh * 8;
            u16x8 ra[4], rb[4];
#pragma unroll
            for (int q = 0; q < 4; ++q) {
                ra[q] = *(const u16x8*)&tab[ga[q] * TROW + tw];
                rb[q] = *(const u16x8*)&tab[gb[q] * TROW + tw];
            }
            float4 sA = *(const float4*)&sgv[tw];
            float4 sB = *(const float4*)&sgv[tw + 4];
            float sg8[8] = {sA.x, sA.y, sA.z, sA.w, sB.x, sB.y, sB.z, sB.w};
#pragma unroll
            for (int j = 0; j < 8; ++j) {
                float sgt = sg8[j];
                float dl = gprev - sgt;
                gprev = sgt;
                bool inc = sgt > 0.0f;
#pragma unroll
                for (int q = 0; q < 4; ++q) {
                    unsigned short u = inc ? ra[q][j] : rb[q][j];
                    float A = __half2float(__ushort_as_half(u));
                    z[q] = (z[q] + dl) * A;
                }
                float a0 = d[0] * z[0];
                float a1 = d[1] * z[1];
                a0 = fmaf(d[2], z[2], a0);
                a1 = fmaf(d[3], z[3], a1);
                v[hh * 8 + j] = a0 + a1;
            }
        }
#pragma unroll
        for (int j = 0; j < 16; ++j) v[j] = dpp16_sum(v[j]);
        float outv = v[0];
#pragma unroll
        for (int j = 1; j < 16; ++j) if ((lane & 15) == j) outv = v[j];
        red[w * 64 + (lane & 15) * 4 + (lane >> 4)] = outv;
        if (lane < 16) {
            float4 s4 = *(const float4*)&red[w * 64 + lane * 4];
            pout[tb + lane] = (s4.x + s4.y) + (s4.z + s4.w);
        }
    }
}

// ---------------------------------------------------------------------------
// k4: outputs (proven R10 body).
// ---------------------------------------------------------------------------
__global__ __launch_bounds__(256) void k4_outputs(
    const float* __restrict__ partials, const float* __restrict__ sum_ptr,
    const float* __restrict__ density, const float* __restrict__ s0,
    const float* __restrict__ mesh, const float* __restrict__ dec,
    const float* __restrict__ y0, float* __restrict__ out)
{
    int i = blockIdx.x * blockDim.x + threadIdx.x;
    const int NM = NB * TT;
    if (i < NM) {
        int b = i >> 11, t = i & (TT - 1);
        float h  = dec[b * TT + t];
        float hp = t ? dec[b * TT + t - 1] : y0[b];
        float g  = (h >= hp) ? 1.0f : -1.0f;
        float acc = 0.f;
#pragma unroll 8
        for (int k = 0; k < NBLK * 4; ++k)
            acc += partials[((size_t)(b * NBLK * 4 + k)) * TT + t];
        float D = sum_ptr[0];
        float m = (acc + g * D) / D;
        out[OUT_M + i] = m;
        out[OUT_BNORM + i] = 0.5f * m + 0.5f;
        return;
    }
    int j = i - NM;
    const int n1 = NB * N_MESH;
    if (j < n1) {
        out[OUT_DENSB + j] = density[j % N_MESH];
    } else if (j < 2 * n1) {
        int jj = j - n1;
        out[OUT_S0 + jj] = s0[jj];
    } else if (j < 4 * n1) {
        int jj = j - 2 * n1;
        out[OUT_MESHB + jj] = mesh[jj % (2 * N_MESH)];
    }
}

extern "C" void kernel_launch(void* const* d_in, const int* in_sizes, int n_in,
                              void* d_out, int out_size, void* d_ws, size_t ws_size,
                              hipStream_t stream) {
    const float* dec  = (const float*)d_in[1];
    const float* s0   = (const float*)d_in[2];
    const float* y0   = (const float*)d_in[3];
    const float* mesh = (const float*)d_in[4];
    const float* Win  = (const float*)d_in[5];
    const float* bin  = (const float*)d_in[6];
    const float* Wblk = (const float*)d_in[7];
    const float* bblk = (const float*)d_in[8];
    const float* Wout = (const float*)d_in[9];
    const float* bout = (const float*)d_in[10];
    float* out = (float*)d_out;
    float* ws  = (float*)d_ws;

    float*  density  = ws + WS_DENSITY;
    float*  sum_ptr  = ws + WS_SUM;
    float*  partials = ws + WS_PART;
    float*  pqf      = ws + WS_PQ;
    float2* pq       = (float2*)pqf;
    half8*  wt       = (half8*)(ws + WS_PART);   // aliases partials (dead by k3)

    k1_scan1_prep<<<SCAN_GRID + PREP_NBLK, 256, 0, stream>>>(
        dec, y0, mesh, Wblk, pq, wt);
    k2_mlp_phase2<<<MLP_NBLK + PH2_NBLK, 512, 0, stream>>>(
        mesh, Win, bin, wt, bblk, Wout, bout, density, s0, pqf);
    k3_phase3_sum<<<SCAN_GRID + 1, 256, 0, stream>>>(
        dec, y0, mesh, density, pqf, partials, sum_ptr);
    k4_outputs<<<708, 256, 0, stream>>>(
        partials, sum_ptr, density, s0, mesh, dec, y0, out);
}